// Round 2
// baseline (247.331 us; speedup 1.0000x reference)
//
#include <hip/hip_runtime.h>
#include <hip/hip_bf16.h>

// Problem constants: N=20000 nodes, K=32 nbrs, C=128, H=256
#define NN    20000
#define KNN   32
#define CIN   128
#define HD    256
#define EE    (NN * KNN)        // 640000 edges
#define NT    20                // nodes (= tiles) per block
#define NBLK  (NN / NT)         // 1000 blocks

typedef __bf16 bf16x8_t __attribute__((ext_vector_type(8)));
typedef __bf16 bf16x4_t __attribute__((ext_vector_type(4)));
typedef float  f32x4_t  __attribute__((ext_vector_type(4)));

// async global->LDS, 16B per lane; LDS dest = uniform base + lane*16
__device__ __forceinline__ void gload_lds16(const __bf16* g, __bf16* l) {
    __builtin_amdgcn_global_load_lds(
        (const __attribute__((address_space(1))) void*)g,
        (__attribute__((address_space(3))) void*)l, 16, 0, 0);
}

// Prep:
//  (a) nfb = bf16(nf)  (float4-vectorized)
//  (b) w1g = frag-ordered W1' where W1' = [W1a-W1b ; W1b]
//      w1g[((kt*4+qr)*256+n)*8+j] = W1'[k=kt*32+qr*8+j][n]
//      (h1 = x_v*(W1a-W1b) + x_vp*W1b; kt0-3 = receiver half, kt4-7 = sender half)
//  (c) w2t[n*256+k] = bf16(W2[k][n])
__global__ void ec_prep(const float* __restrict__ nf, const float* __restrict__ W1,
                        const float* __restrict__ W2, __bf16* __restrict__ nfb,
                        __bf16* __restrict__ w1g, __bf16* __restrict__ w2t) {
    int bid = blockIdx.x;
    if (bid < (NN * CIN) / 1024) {                  // 2500 blocks: nf cast, 4 elems/thread
        int i = (bid * 256 + threadIdx.x) * 4;
        float4 v = *(const float4*)(nf + i);
        bf16x4_t b = { (__bf16)v.x, (__bf16)v.y, (__bf16)v.z, (__bf16)v.w };
        *(bf16x4_t*)(nfb + i) = b;
    } else {                                        // 256 blocks: weights
        int idx = (bid - (NN * CIN) / 1024) * 256 + threadIdx.x;   // 0..65535
        int k = idx >> 8, n = idx & 255;
        float v = (k < CIN) ? (W1[k * 256 + n] - W1[(k + CIN) * 256 + n])
                            : W1[k * 256 + n];
        int kt = k >> 5, qr = (k >> 3) & 3, j = k & 7;
        w1g[(size_t)((kt * 4 + qr) * 256 + n) * 8 + j] = (__bf16)v;
        w2t[n * 256 + k] = (__bf16)W2[k * 256 + n];
    }
}

// 512 thr / 8 waves. 68 KB LDS -> 2 blocks/CU; launch_bounds(512,4) caps regs
// at 128/thread -> 4 waves/SIMD (the round-2 lever: occupancy 2x).
// 1-node tiles: each wave owns ONE 32-feature slice for both GEMMs:
//   GEMM1: wave = 32 feats x 32 edges, K=128 (sender half; W1B' streamed from L2)
//   GEMM2: wave = 32 edges x 32 feats, K=256 (W2 slice = 64 regs, resident)
// One barrier per tile; E and H double-buffered.
__global__ __launch_bounds__(512, 4) void ec_main(
    const __bf16* __restrict__ nfb,      // [NN][CIN] bf16
    const int*   __restrict__ senders,   // [EE]
    const __bf16* __restrict__ w1g,      // frag-ordered W1'
    const __bf16* __restrict__ w2t,      // [256 n][256 k]
    const float* __restrict__ b1,
    const float* __restrict__ b2,
    float* __restrict__ out)             // [NN][HD] fp32
{
    __shared__ __attribute__((aligned(16))) __bf16 ldsE[2][4096];   // 2x8 KB: 32 sender rows
    __shared__ __attribute__((aligned(16))) __bf16 ldsH[2][8192];   // 2x16 KB: H (32 e x 256)
    __shared__ __attribute__((aligned(16))) float  ldsY[NT * 256];  // 20 KB receiver partial

    const int tid  = threadIdx.x;
    const int lane = tid & 63;
    const int wave = tid >> 6;           // 0..7
    const int qrow = lane >> 4;
    const int lcol = lane & 15;
    const int blk  = blockIdx.x;
    const int fsl  = wave * 32;          // this wave's feature slice (both GEMMs)
    const int e5   = lane & 31;          // edge index for sender-idx loads
    const int ch   = wave * 2 + (lane >> 5);          // staging chunk 0..15
    const int soff = (ch >> 2) * 32 + (ch & 3) * 8;   // k-offset within sender row

    // ---- stage tile-0 sender rows into ldsE[0] (async; 1 KB per wave) ----
    {
        int s0 = senders[(blk * NT) * KNN + e5];
        gload_lds16(nfb + (size_t)s0 * CIN + soff, &ldsE[0][wave * 512]);
    }
    // prefetch sender indices for tile 1 (rolling, 1 reg)
    int sn = senders[(blk * NT + 1) * KNN + e5];

    // ---- once per block: Y = X_v * W1A'  (swapped: D = W1A'^T-slice x X_v^T) ----
    {
        f32x4_t ay[2][2];
#pragma unroll
        for (int mi = 0; mi < 2; ++mi)
#pragma unroll
            for (int ni = 0; ni < 2; ++ni)
                ay[mi][ni] = (f32x4_t){0.f, 0.f, 0.f, 0.f};
        bf16x8_t xv[2][4];
#pragma unroll
        for (int ni = 0; ni < 2; ++ni) {
            int ln = ni * 16 + lcol; if (ln > NT - 1) ln = NT - 1;
            const __bf16* row = nfb + (size_t)(blk * NT + ln) * CIN;
#pragma unroll
            for (int c = 0; c < 4; ++c)
                xv[ni][c] = *(const bf16x8_t*)(row + c * 32 + qrow * 8);
        }
#pragma unroll
        for (int kt = 0; kt < 4; ++kt) {
            bf16x8_t wy[2];
#pragma unroll
            for (int mi = 0; mi < 2; ++mi)
                wy[mi] = *(const bf16x8_t*)(w1g +
                    (size_t)((kt * 4 + qrow) * 256 + fsl + mi * 16 + lcol) * 8);
#pragma unroll
            for (int mi = 0; mi < 2; ++mi)
#pragma unroll
                for (int ni = 0; ni < 2; ++ni)
                    ay[mi][ni] = __builtin_amdgcn_mfma_f32_16x16x32_bf16(
                        wy[mi], xv[ni][kt], ay[mi][ni], 0, 0, 0);
        }
        // C-layout: row = feature fsl+mi*16+qrow*4+r, col = node ni*16+lcol
#pragma unroll
        for (int mi = 0; mi < 2; ++mi)
#pragma unroll
            for (int ni = 0; ni < 2; ++ni) {
                int ln = ni * 16 + lcol;
                if (ln < NT)
                    *(f32x4_t*)(ldsY + ln * 256 + fsl + mi * 16 + qrow * 4) = ay[mi][ni];
            }
    }

    // ---- register-resident W2 slice (32 features): 64 VGPRs ----
    bf16x8_t w2f[8][2];
#pragma unroll
    for (int kt = 0; kt < 8; ++kt)
#pragma unroll
        for (int ni = 0; ni < 2; ++ni)
            w2f[kt][ni] = *(const bf16x8_t*)(w2t + (size_t)(fsl + ni * 16 + lcol) * 256
                                                 + kt * 32 + qrow * 8);

    float4 bias1[2];
#pragma unroll
    for (int mi = 0; mi < 2; ++mi)
        bias1[mi] = *(const float4*)(b1 + fsl + mi * 16 + qrow * 4);
    float bias2[2];
#pragma unroll
    for (int ni = 0; ni < 2; ++ni)
        bias2[ni] = b2[fsl + ni * 16 + lcol];

    // W1B' (sender half) fragment base; streamed from L2 per tile
    const __bf16* w1b = w1g + 32768;

    __syncthreads();   // ldsE[0] (vmcnt drained) + ldsY ready

#pragma unroll 1
    for (int t = 0; t < NT; ++t) {
        const int cur = t & 1;

        // rolling sender-idx prefetch (keeps HBM latency off the stage chain)
        int sn2 = sn;
        if (t + 2 < NT) sn2 = senders[(blk * NT + t + 2) * KNN + e5];

        // ---- stage tile t+1 senders into the other ldsE buffer ----
        if (t + 1 < NT)
            gload_lds16(nfb + (size_t)sn * CIN + soff, &ldsE[1 - cur][wave * 512]);

        // ---- GEMM1: acc init from Y (broadcast), + sender half (W1B' from L2) ----
        f32x4_t acc[2][2];
#pragma unroll
        for (int mi = 0; mi < 2; ++mi) {
            f32x4_t y = *(const f32x4_t*)(ldsY + t * 256 + fsl + mi * 16 + qrow * 4);
            acc[mi][0] = y;
            acc[mi][1] = y;
        }
#pragma unroll
        for (int kt = 0; kt < 4; ++kt) {
            bf16x8_t wf[2], ef[2];
#pragma unroll
            for (int mi = 0; mi < 2; ++mi)
                wf[mi] = *(const bf16x8_t*)(w1b +
                    (size_t)((kt * 4 + qrow) * 256 + fsl + mi * 16 + lcol) * 8);
#pragma unroll
            for (int ni = 0; ni < 2; ++ni)
                ef[ni] = *(const bf16x8_t*)(&ldsE[cur][0] +
                    (size_t)((kt * 4 + qrow) * 32 + ni * 16 + lcol) * 8);
#pragma unroll
            for (int mi = 0; mi < 2; ++mi)
#pragma unroll
                for (int ni = 0; ni < 2; ++ni)
                    acc[mi][ni] = __builtin_amdgcn_mfma_f32_16x16x32_bf16(
                        wf[mi], ef[ni], acc[mi][ni], 0, 0, 0);
        }

        // ---- epilogue 1: +b1, relu, packed bf16x4 -> ldsH[cur] (frag-ordered)
        //      H elem layout: ((f>>3)*32 + edge)*8 + (f&7) ----
#pragma unroll
        for (int mi = 0; mi < 2; ++mi) {
            const int f0 = fsl + mi * 16 + qrow * 4;
            const int cq = f0 >> 3, jh = f0 & 7;
            float4 bb = bias1[mi];
#pragma unroll
            for (int ni = 0; ni < 2; ++ni) {
                int edge = ni * 16 + lcol;
                float v0 = acc[mi][ni][0] + bb.x;
                float v1 = acc[mi][ni][1] + bb.y;
                float v2 = acc[mi][ni][2] + bb.z;
                float v3 = acc[mi][ni][3] + bb.w;
                bf16x4_t h = { (__bf16)fmaxf(v0, 0.f), (__bf16)fmaxf(v1, 0.f),
                               (__bf16)fmaxf(v2, 0.f), (__bf16)fmaxf(v3, 0.f) };
                *(bf16x4_t*)(&ldsH[cur][0] + (size_t)(cq * 32 + edge) * 8 + jh) = h;
            }
        }

        __syncthreads();   // publishes ldsH[cur], drains stage(t+1)

        // ---- GEMM2: D = H(32 edges, ldsH) x W2(32 features, regs), K=256 ----
        f32x4_t acc2[2][2];
#pragma unroll
        for (int mi = 0; mi < 2; ++mi)
#pragma unroll
            for (int ni = 0; ni < 2; ++ni)
                acc2[mi][ni] = (f32x4_t){0.f, 0.f, 0.f, 0.f};
#pragma unroll
        for (int kt2 = 0; kt2 < 8; ++kt2) {
            bf16x8_t af[2];
#pragma unroll
            for (int mi = 0; mi < 2; ++mi)
                af[mi] = *(const bf16x8_t*)(&ldsH[cur][0] +
                    (size_t)((kt2 * 4 + qrow) * 32 + mi * 16 + lcol) * 8);
#pragma unroll
            for (int mi = 0; mi < 2; ++mi)
#pragma unroll
                for (int ni = 0; ni < 2; ++ni)
                    acc2[mi][ni] = __builtin_amdgcn_mfma_f32_16x16x32_bf16(
                        af[mi], w2f[kt2][ni], acc2[mi][ni], 0, 0, 0);
        }

        // ---- epilogue 2: max over the node's 32 edges, +b2, store ----
#pragma unroll
        for (int ni = 0; ni < 2; ++ni) {
            float mx = -3.402823466e38f;
#pragma unroll
            for (int mi = 0; mi < 2; ++mi)
#pragma unroll
                for (int r = 0; r < 4; ++r)
                    mx = fmaxf(mx, acc2[mi][ni][r]);
            mx = fmaxf(mx, __shfl_xor(mx, 16, 64));
            mx = fmaxf(mx, __shfl_xor(mx, 32, 64));
            if (qrow == 0)
                out[(size_t)(blk * NT + t) * HD + fsl + ni * 16 + lcol] = mx + bias2[ni];
        }

        sn = sn2;
        // hazards (single barrier, dbuf): epi1(t)->ldsH[t&1]: its previous
        // readers (GEMM2(t-2)) precede barrier(t-1) in every wave's program
        // order, and epi1(t) follows barrier(t-1). stage(t+1)->ldsE[(t+1)&1]:
        // previous readers (GEMM1(t-1)) precede barrier(t-1). Async LDS
        // writes drain at barrier(t); readers (GEMM1(t+1)) follow it.
    }
}

extern "C" void kernel_launch(void* const* d_in, const int* in_sizes, int n_in,
                              void* d_out, int out_size, void* d_ws, size_t ws_size,
                              hipStream_t stream) {
    const float* nf      = (const float*)d_in[0];
    const int*   senders = (const int*)d_in[1];
    // d_in[2] = receivers: implicit (repeat(arange(N), K)), unused
    const float* W1 = (const float*)d_in[3];
    const float* b1 = (const float*)d_in[4];
    const float* W2 = (const float*)d_in[5];
    const float* b2 = (const float*)d_in[6];

    __bf16* w1g = (__bf16*)d_ws;                 // 128 KB frag-ordered W1'
    __bf16* w2t = w1g + 256 * 256;               // 128 KB
    __bf16* nfb = w2t + 256 * 256;               // 5.12 MB bf16 node features

    ec_prep<<<(NN * CIN) / 1024 + 256, 256, 0, stream>>>(nf, W1, W2, nfb, w1g, w2t);
    ec_main<<<NBLK, 512, 0, stream>>>(nfb, senders, w1g, w2t, b1, b2, (float*)d_out);
}

// Round 3
// 220.927 us; speedup vs baseline: 1.1195x; 1.1195x over previous
//
#include <hip/hip_runtime.h>
#include <hip/hip_bf16.h>

// Problem constants: N=20000 nodes, K=32 nbrs, C=128, H=256
#define NN    20000
#define KNN   32
#define CIN   128
#define HD    256
#define EE    (NN * KNN)        // 640000 edges
#define NT    10                // tiles per block (2 nodes each) -> 20 nodes/block
#define NBLK  (NN / (2 * NT))   // 1000 blocks

typedef __bf16 bf16x8_t __attribute__((ext_vector_type(8)));
typedef __bf16 bf16x4_t __attribute__((ext_vector_type(4)));
typedef float  f32x4_t  __attribute__((ext_vector_type(4)));

// Prep:
//  (a) nfb = bf16(nf)  (float4-vectorized)
//  (b) w1g = frag-ordered W1' where W1' = [W1a-W1b ; W1b]
//      w1g[((kt*4+qr)*256+n)*8+j] = W1'[k=kt*32+qr*8+j][n]
//      (chunks 0-15 = receiver half (W1a-W1b), 16-31 = sender half (W1b))
//  (c) w2t[n*256+k] = bf16(W2[k][n])
__global__ void ec_prep(const float* __restrict__ nf, const float* __restrict__ W1,
                        const float* __restrict__ W2, __bf16* __restrict__ nfb,
                        __bf16* __restrict__ w1g, __bf16* __restrict__ w2t) {
    int bid = blockIdx.x;
    if (bid < (NN * CIN) / 1024) {                  // 2500 blocks: nf cast, 4 elems/thread
        int i = (bid * 256 + threadIdx.x) * 4;
        float4 v = *(const float4*)(nf + i);
        bf16x4_t b = { (__bf16)v.x, (__bf16)v.y, (__bf16)v.z, (__bf16)v.w };
        *(bf16x4_t*)(nfb + i) = b;
    } else {                                        // 256 blocks: weights
        int idx = (bid - (NN * CIN) / 1024) * 256 + threadIdx.x;   // 0..65535
        int k = idx >> 8, n = idx & 255;
        float v = (k < CIN) ? (W1[k * 256 + n] - W1[(k + CIN) * 256 + n])
                            : W1[k * 256 + n];
        int kt = k >> 5, qr = (k >> 3) & 3, j = k & 7;
        w1g[(size_t)((kt * 4 + qr) * 256 + n) * 8 + j] = (__bf16)v;
        w2t[n * 256 + k] = (__bf16)W2[k * 256 + n];
    }
}

// Per-node precompute of BOTH GEMM1 halves (the round-3 lever: senders repeat,
// so the 42 GF edge-GEMM1 collapses to a 2.6 GF node-GEMM):
//   Pq[n][f] = sum_k X[n][k]*(W1a-W1b)[k][f] + b1[f]   (fp32)
//   Zq[n][f] = sum_k X[n][k]*W1b[k][f]                 (bf16)
// 625 blocks x 512 thr; 32 nodes/block; wave w owns feature slice w*32.
__global__ __launch_bounds__(512, 1) void ec_pz(
    const __bf16* __restrict__ nfb, const __bf16* __restrict__ w1g,
    const float* __restrict__ b1, float* __restrict__ Pq, __bf16* __restrict__ Zq)
{
    __shared__ __attribute__((aligned(16))) float ldsT[32 * 256];   // 32 KB transpose buf

    const int tid  = threadIdx.x;
    const int lane = tid & 63;
    const int wave = tid >> 6;
    const int qrow = lane >> 4;
    const int lcol = lane & 15;
    const int blk  = blockIdx.x;
    const int fsl  = wave * 32;

    // node features for this block's 32 nodes (lane-col = node)
    bf16x8_t xv[2][4];
#pragma unroll
    for (int ni = 0; ni < 2; ++ni) {
        const __bf16* row = nfb + (size_t)(blk * 32 + ni * 16 + lcol) * CIN;
#pragma unroll
        for (int c = 0; c < 4; ++c)
            xv[ni][c] = *(const bf16x8_t*)(row + c * 32 + qrow * 8);
    }

    float4 bias1[2];
#pragma unroll
    for (int mi = 0; mi < 2; ++mi)
        bias1[mi] = *(const float4*)(b1 + fsl + mi * 16 + qrow * 4);

    // ---- P half (chunks 0..15), +b1 ----
    {
        f32x4_t ay[2][2];
#pragma unroll
        for (int mi = 0; mi < 2; ++mi)
#pragma unroll
            for (int ni = 0; ni < 2; ++ni)
                ay[mi][ni] = (f32x4_t){0.f, 0.f, 0.f, 0.f};
#pragma unroll
        for (int kt = 0; kt < 4; ++kt) {
            bf16x8_t wy[2];
#pragma unroll
            for (int mi = 0; mi < 2; ++mi)
                wy[mi] = *(const bf16x8_t*)(w1g +
                    (size_t)((kt * 4 + qrow) * 256 + fsl + mi * 16 + lcol) * 8);
#pragma unroll
            for (int mi = 0; mi < 2; ++mi)
#pragma unroll
                for (int ni = 0; ni < 2; ++ni)
                    ay[mi][ni] = __builtin_amdgcn_mfma_f32_16x16x32_bf16(
                        wy[mi], xv[ni][kt], ay[mi][ni], 0, 0, 0);
        }
        // C-layout: row = feature fsl+mi*16+qrow*4+r, col = node ni*16+lcol
#pragma unroll
        for (int mi = 0; mi < 2; ++mi)
#pragma unroll
            for (int ni = 0; ni < 2; ++ni) {
                f32x4_t v = ay[mi][ni];
                v[0] += bias1[mi].x; v[1] += bias1[mi].y;
                v[2] += bias1[mi].z; v[3] += bias1[mi].w;
                *(f32x4_t*)(ldsT + (ni * 16 + lcol) * 256 + fsl + mi * 16 + qrow * 4) = v;
            }
    }
    __syncthreads();
    // coalesced fp32 store of P'
    {
        float4* dst = (float4*)(Pq + (size_t)blk * 32 * 256);
        const float4* src = (const float4*)ldsT;
#pragma unroll
        for (int i = 0; i < 4; ++i)
            dst[tid * 4 + i] = src[tid * 4 + i];
    }
    __syncthreads();   // store-phase reads done before Z overwrites ldsT

    // ---- Z half (chunks 16..31), no bias ----
    {
        f32x4_t az[2][2];
#pragma unroll
        for (int mi = 0; mi < 2; ++mi)
#pragma unroll
            for (int ni = 0; ni < 2; ++ni)
                az[mi][ni] = (f32x4_t){0.f, 0.f, 0.f, 0.f};
#pragma unroll
        for (int kt = 0; kt < 4; ++kt) {
            bf16x8_t wy[2];
#pragma unroll
            for (int mi = 0; mi < 2; ++mi)
                wy[mi] = *(const bf16x8_t*)(w1g +
                    (size_t)((16 + kt * 4 + qrow) * 256 + fsl + mi * 16 + lcol) * 8);
#pragma unroll
            for (int mi = 0; mi < 2; ++mi)
#pragma unroll
                for (int ni = 0; ni < 2; ++ni)
                    az[mi][ni] = __builtin_amdgcn_mfma_f32_16x16x32_bf16(
                        wy[mi], xv[ni][kt], az[mi][ni], 0, 0, 0);
        }
#pragma unroll
        for (int mi = 0; mi < 2; ++mi)
#pragma unroll
            for (int ni = 0; ni < 2; ++ni)
                *(f32x4_t*)(ldsT + (ni * 16 + lcol) * 256 + fsl + mi * 16 + qrow * 4)
                    = az[mi][ni];
    }
    __syncthreads();
    // coalesced bf16 store of Z
    {
        const float4* src = (const float4*)ldsT;
        __bf16* dst = Zq + (size_t)blk * 32 * 256;
#pragma unroll
        for (int i = 0; i < 4; ++i) {
            float4 v = src[tid * 4 + i];
            bf16x4_t b = { (__bf16)v.x, (__bf16)v.y, (__bf16)v.z, (__bf16)v.w };
            *(bf16x4_t*)(dst + (size_t)(tid * 4 + i) * 4) = b;
        }
    }
}

// Main: per 2-node tile, gather Z rows (random senders, L2/L3-resident 10 MB),
// H = relu(P'[recv] + Z[send]) -> ldsH (frag-ordered), then GEMM2 = H x W2.
// 512 thr / 8 waves, 84 KB LDS, ~220 regs -> 1 block/CU, 2 waves/SIMD.
// One barrier per tile; H double-buffered; gather(t+1) issued before GEMM2(t).
__global__ __launch_bounds__(512, 1) void ec_main(
    const __bf16* __restrict__ Zq,       // [NN][HD] bf16
    const int*   __restrict__ senders,   // [EE]
    const float* __restrict__ Pq,        // [NN][HD] fp32 (b1 folded in)
    const __bf16* __restrict__ w2t,      // [256 n][256 k]
    const float* __restrict__ b2,
    float* __restrict__ out)             // [NN][HD] fp32
{
    __shared__ __attribute__((aligned(16))) __bf16 ldsH[2][16384];  // 2x32 KB H dbuf
    __shared__ __attribute__((aligned(16))) float  ldsP[20 * 256];  // 20 KB P' (fp32)

    const int tid  = threadIdx.x;
    const int lane = tid & 63;
    const int wave = tid >> 6;           // 0..7
    const int qrow = lane >> 4;
    const int lcol = lane & 15;
    const int blk  = blockIdx.x;
    const int fsl  = wave * 32;          // H-assembly feature slice
    const int fs2  = (wave >> 1) * 64;   // GEMM2 feature slice
    const int eh   = wave & 1;           // GEMM2 edge half (node within tile)

    // ---- sender indices for all 10 tiles (lane = edge) ----
    int sidxAll[NT];
#pragma unroll
    for (int tt = 0; tt < NT; ++tt)
        sidxAll[tt] = senders[(blk * NT + tt) * 64 + lane];

    // ---- P'(20 rows) -> ldsP (fp32, coalesced) ----
    {
        const float4* src = (const float4*)(Pq + (size_t)blk * 20 * 256);
        float4* dst = (float4*)ldsP;
        for (int i = tid; i < 1280; i += 512)
            dst[i] = src[i];
    }

    // ---- register-resident W2 slice (64 features): 128 VGPRs ----
    bf16x8_t w2f[8][4];
#pragma unroll
    for (int kt = 0; kt < 8; ++kt)
#pragma unroll
        for (int ni = 0; ni < 4; ++ni)
            w2f[kt][ni] = *(const bf16x8_t*)(w2t + (size_t)(fs2 + ni * 16 + lcol) * 256
                                                 + kt * 32 + qrow * 8);
    float bias2[4];
#pragma unroll
    for (int ni = 0; ni < 4; ++ni)
        bias2[ni] = b2[fs2 + ni * 16 + lcol];

    // ---- gather Z for tile 0 (lane = edge, 4x16B from its sender row) ----
    bf16x8_t zf[4];
#pragma unroll
    for (int c = 0; c < 4; ++c)
        zf[c] = *(const bf16x8_t*)(Zq + (size_t)sidxAll[0] * HD + fsl + c * 8);

    __syncthreads();   // ldsP ready

    // ---- assemble H(0) -> ldsH[0]: h = relu(P'[node] + Z[sender]) ----
    {
        const int nl = 0 * 2 + (lane >> 5);          // node-local 0/1
        const float* pf = ldsP + nl * 256 + fsl;
#pragma unroll
        for (int c = 0; c < 4; ++c) {
            f32x4_t p0 = *(const f32x4_t*)(pf + c * 8);
            f32x4_t p1 = *(const f32x4_t*)(pf + c * 8 + 4);
            bf16x8_t h;
#pragma unroll
            for (int j = 0; j < 4; ++j) {
                h[j]     = (__bf16)fmaxf(p0[j] + (float)zf[c][j], 0.f);
                h[j + 4] = (__bf16)fmaxf(p1[j] + (float)zf[c][j + 4], 0.f);
            }
            *(bf16x8_t*)(&ldsH[0][0] + (size_t)((wave * 4 + c) * 64 + lane) * 8) = h;
        }
    }
    __syncthreads();   // ldsH[0] published

#pragma unroll 1
    for (int t = 0; t < NT; ++t) {
        const int cur = t & 1;

        // ---- issue Z-gather for tile t+1 (latency hides under GEMM2) ----
        if (t + 1 < NT) {
#pragma unroll
            for (int c = 0; c < 4; ++c)
                zf[c] = *(const bf16x8_t*)(Zq + (size_t)sidxAll[t + 1] * HD + fsl + c * 8);
        }

        // ---- GEMM2: D = H(32 edges, ldsH[cur]) x W2(64 features, regs), K=256 ----
        f32x4_t acc2[2][4];
#pragma unroll
        for (int mi = 0; mi < 2; ++mi)
#pragma unroll
            for (int ni = 0; ni < 4; ++ni)
                acc2[mi][ni] = (f32x4_t){0.f, 0.f, 0.f, 0.f};
#pragma unroll
        for (int kt = 0; kt < 8; ++kt) {
            bf16x8_t af[2];
#pragma unroll
            for (int mi = 0; mi < 2; ++mi)
                af[mi] = *(const bf16x8_t*)(&ldsH[cur][0] +
                    (size_t)((kt * 4 + qrow) * 64 + eh * 32 + mi * 16 + lcol) * 8);
#pragma unroll
            for (int mi = 0; mi < 2; ++mi)
#pragma unroll
                for (int ni = 0; ni < 4; ++ni)
                    acc2[mi][ni] = __builtin_amdgcn_mfma_f32_16x16x32_bf16(
                        af[mi], w2f[kt][ni], acc2[mi][ni], 0, 0, 0);
        }

        // ---- epilogue: max over this wave's node (32 edges), +b2, store ----
#pragma unroll
        for (int ni = 0; ni < 4; ++ni) {
            float mx = -3.402823466e38f;
#pragma unroll
            for (int mi = 0; mi < 2; ++mi)
#pragma unroll
                for (int r = 0; r < 4; ++r)
                    mx = fmaxf(mx, acc2[mi][ni][r]);
            mx = fmaxf(mx, __shfl_xor(mx, 16, 64));
            mx = fmaxf(mx, __shfl_xor(mx, 32, 64));
            if (qrow == 0)
                out[(size_t)((blk * NT + t) * 2 + eh) * HD + fs2 + ni * 16 + lcol]
                    = mx + bias2[ni];
        }

        // ---- assemble H(t+1) -> ldsH[1-cur] (safe: its last readers, GEMM2(t-1),
        //      finished before barrier(t-1); this code runs after it) ----
        if (t + 1 < NT) {
            const int nl = (t + 1) * 2 + (lane >> 5);
            const float* pf = ldsP + nl * 256 + fsl;
#pragma unroll
            for (int c = 0; c < 4; ++c) {
                f32x4_t p0 = *(const f32x4_t*)(pf + c * 8);
                f32x4_t p1 = *(const f32x4_t*)(pf + c * 8 + 4);
                bf16x8_t h;
#pragma unroll
                for (int j = 0; j < 4; ++j) {
                    h[j]     = (__bf16)fmaxf(p0[j] + (float)zf[c][j], 0.f);
                    h[j + 4] = (__bf16)fmaxf(p1[j] + (float)zf[c][j + 4], 0.f);
                }
                *(bf16x8_t*)(&ldsH[1 - cur][0] + (size_t)((wave * 4 + c) * 64 + lane) * 8) = h;
            }
        }

        __syncthreads();   // publishes ldsH[1-cur] for tile t+1
    }
}

extern "C" void kernel_launch(void* const* d_in, const int* in_sizes, int n_in,
                              void* d_out, int out_size, void* d_ws, size_t ws_size,
                              hipStream_t stream) {
    const float* nf      = (const float*)d_in[0];
    const int*   senders = (const int*)d_in[1];
    // d_in[2] = receivers: implicit (repeat(arange(N), K)), unused
    const float* W1 = (const float*)d_in[3];
    const float* b1 = (const float*)d_in[4];
    const float* W2 = (const float*)d_in[5];
    const float* b2 = (const float*)d_in[6];

    __bf16* w1g = (__bf16*)d_ws;                 // 128 KB frag-ordered W1'
    __bf16* w2t = w1g + 256 * 256;               // 128 KB
    __bf16* nfb = w2t + 256 * 256;               // 5.12 MB bf16 node features
    __bf16* Zq  = nfb + (size_t)NN * CIN;        // 10.24 MB bf16 Z = X*W1b
    float*  Pq  = (float*)(Zq + (size_t)NN * HD);// 20.48 MB fp32 P' = X*(W1a-W1b)+b1

    ec_prep<<<(NN * CIN) / 1024 + 256, 256, 0, stream>>>(nf, W1, W2, nfb, w1g, w2t);
    ec_pz<<<NN / 32, 512, 0, stream>>>(nfb, w1g, b1, Pq, Zq);
    ec_main<<<NBLK, 512, 0, stream>>>(Zq, senders, Pq, w2t, b2, (float*)d_out);
}